// Round 6
// baseline (889.607 us; speedup 1.0000x reference)
//
#include <hip/hip_runtime.h>
#include <hip/hip_cooperative_groups.h>
#include <math.h>

namespace cg = cooperative_groups;

#define H 256

struct Params {
    const int *word_ids, *left_idx, *right_idx;
    const float *emb;
    const float *Wi, *bi, *Wo, *bo, *Wu, *bu;
    const float *Ui, *bui, *Uo, *buo, *Uu, *buu;
    const float *Uf1, *bf1, *Uf2, *bf2, *Wp, *bp;
    float *h_buf;   // [n_nodes][H]
    float *out;     // [n_nodes][5]
    int n_leaves, n_internal, n_nodes;
};

__device__ __forceinline__ float sigmoidf_(float x) {
    return 1.0f / (1.0f + __expf(-x));
}

// Block: 512 threads = 8 waves. Wave jl owns output j = jb + jl (jb = (b&31)*8).
// Lanes kc = 0..63 k-split the dot products; weights live in LDS (64 KB slice,
// staged once -- the compiler cannot evict LDS, unlike the failed VGPR plans).
// Cohort coh = b>>5 strides nodes by NCOH = G/32 within each level.
__global__ __launch_bounds__(512, 4) void tree_kernel(Params P)
{
    cg::grid_group grid = cg::this_grid();
    const int tid  = threadIdx.x;
    const int b    = blockIdx.x;
    const int G    = gridDim.x;
    const int NCOH = G >> 5;
    const int coh  = b >> 5;
    const int jb   = (b & 31) * 8;
    const int kc   = tid & 63;
    const int jl   = tid >> 6;      // wave id = local output
    const int j    = jb + jl;

    __shared__ float sw[4 * 8 * 512];   // 64 KB weight slice
    __shared__ float s_cat[512];
    __shared__ float s_red[8][5];

    // ---------------- stage LEAF weight slice: sw[g*2048 + jl*256 + k] ----------------
    for (int u = tid; u < 3 * 8 * 256; u += 512) {
        int g  = u / 2048;
        int r  = u - g * 2048;
        int jj = r >> 8;
        int k  = r & 255;
        const float* src = (g == 0) ? P.Wi : (g == 1) ? P.Wo : P.Wu;
        sw[u] = src[(size_t)(jb + jj) * H + k];
    }
    __syncthreads();

    // ---------------- leaf phase ----------------
    {
        const float bij = P.bi[j], boj = P.bo[j], buj = P.bu[j];
        const float* wi = sw + 0 * 2048 + jl * 256;
        const float* wo = sw + 1 * 2048 + jl * 256;
        const float* wu = sw + 2 * 2048 + jl * 256;

        float v = 0.f;
        {
            int wid = __builtin_amdgcn_readfirstlane(P.word_ids[coh]);
            if (tid < 256) v = P.emb[(size_t)wid * H + tid];
        }
        for (int l = coh; l < P.n_leaves; l += NCOH) {
            __syncthreads();                     // (1) s_cat free
            if (tid < 256) s_cat[tid] = v;
            __syncthreads();                     // (2) s_cat ready
            int ln = l + NCOH;                   // prefetch AFTER barrier: latency hides under compute
            if (ln < P.n_leaves) {
                int wid = __builtin_amdgcn_readfirstlane(P.word_ids[ln]);
                if (tid < 256) v = P.emb[(size_t)wid * H + tid];
            }
            float a0 = 0.f, a1 = 0.f, a2 = 0.f;
#pragma unroll
            for (int mp = 0; mp < 2; ++mp) {
                int k = 2 * kc + 128 * mp;
                float2 x  = *(const float2*)&s_cat[k];
                float2 w0 = *(const float2*)&wi[k];
                float2 w1 = *(const float2*)&wo[k];
                float2 w2 = *(const float2*)&wu[k];
                a0 = fmaf(x.x, w0.x, a0); a0 = fmaf(x.y, w0.y, a0);
                a1 = fmaf(x.x, w1.x, a1); a1 = fmaf(x.y, w1.y, a1);
                a2 = fmaf(x.x, w2.x, a2); a2 = fmaf(x.y, w2.y, a2);
            }
#pragma unroll
            for (int m = 1; m <= 32; m <<= 1) {
                a0 += __shfl_xor(a0, m);
                a1 += __shfl_xor(a1, m);
                a2 += __shfl_xor(a2, m);
            }
            if (kc == 0) {
                float ii = sigmoidf_(a0 + bij);
                float oo = sigmoidf_(a1 + boj);
                float uu = fmaxf(a2 + buj, 0.f);
                float h  = oo * fmaxf(ii * uu, 0.f);
                P.h_buf[(size_t)l * H + j] = h;
            }
        }
    }
    grid.sync();

    // ---------------- stage INTERNAL weight slice: sw[g*4096 + jl*512 + k] ----------------
    for (int u = tid; u < 4 * 8 * 512; u += 512) {
        int g  = u >> 12;
        int r  = u & 4095;
        int jj = r >> 9;
        int k  = r & 511;
        float val;
        if (g < 3) {
            const float* src = (g == 0) ? P.Ui : (g == 1) ? P.Uo : P.Uu;
            val = src[(size_t)(jb + jj) * 2 * H + k];
        } else {
            val = (k < 256) ? P.Uf1[(size_t)(jb + jj) * H + k]
                            : P.Uf2[(size_t)(jb + jj) * H + (k - 256)];
        }
        sw[u] = val;
    }
    __syncthreads();

    // ---------------- internal levels ----------------
    {
        const float b_i = P.bui[j], b_o = P.buo[j], b_u = P.buu[j];
        const float b_1 = P.bf1[j], b_2 = P.bf2[j];
        const float* wI = sw + 0 * 4096 + jl * 512;
        const float* wO = sw + 1 * 4096 + jl * 512;
        const float* wU = sw + 2 * 4096 + jl * 512;
        const float* wF = sw + 3 * 4096 + jl * 512;

        int frontier = P.n_leaves;
        int tbase = 0;
        while (frontier > 1) {
            const int lvl = frontier >> 1;
            float v = 0.f;
            if (coh < lvl) {
                int t  = tbase + coh;
                int lc = __builtin_amdgcn_readfirstlane(P.left_idx[t]);
                int rc = __builtin_amdgcn_readfirstlane(P.right_idx[t]);
                v = (tid < 256) ? P.h_buf[(size_t)lc * H + tid]
                                : P.h_buf[(size_t)rc * H + (tid - 256)];
            }
            for (int idx = coh; idx < lvl; idx += NCOH) {
                __syncthreads();                 // (1) s_cat free
                s_cat[tid] = v;
                __syncthreads();                 // (2) s_cat ready
                int idxn = idx + NCOH;           // prefetch AFTER barrier
                if (idxn < lvl) {
                    int tn  = tbase + idxn;
                    int lcn = __builtin_amdgcn_readfirstlane(P.left_idx[tn]);
                    int rcn = __builtin_amdgcn_readfirstlane(P.right_idx[tn]);
                    v = (tid < 256) ? P.h_buf[(size_t)lcn * H + tid]
                                    : P.h_buf[(size_t)rcn * H + (tid - 256)];
                }
                float a0 = 0.f, a1 = 0.f, a2 = 0.f, f1 = 0.f, f2 = 0.f;
#pragma unroll
                for (int mp = 0; mp < 4; ++mp) {
                    int k = 2 * kc + 128 * mp;
                    float2 x  = *(const float2*)&s_cat[k];
                    float2 w0 = *(const float2*)&wI[k];
                    float2 w1 = *(const float2*)&wO[k];
                    float2 w2 = *(const float2*)&wU[k];
                    float2 w3 = *(const float2*)&wF[k];
                    a0 = fmaf(x.x, w0.x, a0); a0 = fmaf(x.y, w0.y, a0);
                    a1 = fmaf(x.x, w1.x, a1); a1 = fmaf(x.y, w1.y, a1);
                    a2 = fmaf(x.x, w2.x, a2); a2 = fmaf(x.y, w2.y, a2);
                    float ff = fmaf(x.x, w3.x, x.y * w3.y);
                    if (mp < 2) f1 += ff; else f2 += ff;
                }
#pragma unroll
                for (int m = 1; m <= 32; m <<= 1) {
                    a0 += __shfl_xor(a0, m);
                    a1 += __shfl_xor(a1, m);
                    a2 += __shfl_xor(a2, m);
                    f1 += __shfl_xor(f1, m);
                    f2 += __shfl_xor(f2, m);
                }
                if (kc == 0) {
                    float lh = s_cat[j];
                    float rh = s_cat[256 + j];
                    float ii  = sigmoidf_(a0 + b_i);
                    float oo  = sigmoidf_(a1 + b_o);
                    float uu  = fmaxf(a2 + b_u, 0.f);
                    float ff1 = sigmoidf_(f1 + b_1);
                    float ff2 = sigmoidf_(f2 + b_2);
                    float c   = ii * uu + ff1 * lh + ff2 * rh;
                    float h   = oo * fmaxf(c, 0.f);
                    P.h_buf[(size_t)(P.n_leaves + tbase + idx) * H + j] = h;
                }
            }
            grid.sync();
            tbase += lvl;
            frontier = lvl + (frontier & 1);
        }
    }

    // ---------------- projection: 2 nodes per block-iteration ----------------
    {
        const int half = tid >> 8;          // 0 or 1
        const int e    = tid & 255;
        const int wv   = tid >> 6;          // wave 0..7 (waves 0-3 = half 0)
        float wp0 = P.Wp[0 * H + e];
        float wp1 = P.Wp[1 * H + e];
        float wp2 = P.Wp[2 * H + e];
        float wp3 = P.Wp[3 * H + e];
        float wp4 = P.Wp[4 * H + e];
        for (int n0 = b * 2; n0 < P.n_nodes; n0 += G * 2) {
            int n = n0 + half;
            float h = (n < P.n_nodes) ? P.h_buf[(size_t)n * H + e] : 0.f;
            float p0 = wp0 * h, p1 = wp1 * h, p2 = wp2 * h, p3 = wp3 * h, p4 = wp4 * h;
#pragma unroll
            for (int m = 1; m <= 32; m <<= 1) {
                p0 += __shfl_xor(p0, m);
                p1 += __shfl_xor(p1, m);
                p2 += __shfl_xor(p2, m);
                p3 += __shfl_xor(p3, m);
                p4 += __shfl_xor(p4, m);
            }
            __syncthreads();
            if ((tid & 63) == 0) {
                s_red[wv][0] = p0; s_red[wv][1] = p1; s_red[wv][2] = p2;
                s_red[wv][3] = p3; s_red[wv][4] = p4;
            }
            __syncthreads();
            if (e < 5 && n < P.n_nodes) {
                int sb = half * 4;
                P.out[(size_t)n * 5 + e] = P.bp[e]
                    + s_red[sb][e] + s_red[sb + 1][e] + s_red[sb + 2][e] + s_red[sb + 3][e];
            }
        }
    }
}

extern "C" void kernel_launch(void* const* d_in, const int* in_sizes, int n_in,
                              void* d_out, int out_size, void* d_ws, size_t ws_size,
                              hipStream_t stream)
{
    Params P;
    P.word_ids  = (const int*)d_in[0];
    P.left_idx  = (const int*)d_in[1];
    P.right_idx = (const int*)d_in[2];
    P.emb = (const float*)d_in[3];
    P.Wi  = (const float*)d_in[4];  P.bi  = (const float*)d_in[5];
    P.Wo  = (const float*)d_in[6];  P.bo  = (const float*)d_in[7];
    P.Wu  = (const float*)d_in[8];  P.bu  = (const float*)d_in[9];
    P.Ui  = (const float*)d_in[10]; P.bui = (const float*)d_in[11];
    P.Uo  = (const float*)d_in[12]; P.buo = (const float*)d_in[13];
    P.Uu  = (const float*)d_in[14]; P.buu = (const float*)d_in[15];
    P.Uf1 = (const float*)d_in[16]; P.bf1 = (const float*)d_in[17];
    P.Uf2 = (const float*)d_in[18]; P.bf2 = (const float*)d_in[19];
    P.Wp  = (const float*)d_in[20]; P.bp  = (const float*)d_in[21];
    P.n_leaves   = in_sizes[0];
    P.n_internal = in_sizes[1];
    P.n_nodes    = P.n_leaves + P.n_internal;
    P.out = (float*)d_out;
    (void)n_in; (void)out_size; (void)ws_size;

    P.h_buf = (float*)d_ws;

    // adaptive cooperative grid (host-side queries: capture-safe)
    int dev = 0;
    hipGetDevice(&dev);
    hipDeviceProp_t props;
    hipGetDeviceProperties(&props, dev);
    int perCU = 0;
    hipOccupancyMaxActiveBlocksPerMultiprocessor(&perCU, (const void*)tree_kernel, 512, 0);
    if (perCU < 1) perCU = 1;
    long Gl = (long)perCU * props.multiProcessorCount;
    int G = (Gl > 512) ? 512 : (int)Gl;
    G &= ~31;                 // multiple of 32 (j-split width)
    if (G < 32) G = 32;

    void* args[] = { &P };
    hipLaunchCooperativeKernel((void*)tree_kernel, dim3(G), dim3(512), args, 0, stream);
}

// Round 7
// 357.122 us; speedup vs baseline: 2.4910x; 2.4910x over previous
//
#include <hip/hip_runtime.h>
#include <math.h>

#define H 256

__device__ __forceinline__ float sigmoidf_(float x) {
    return 1.0f / (1.0f + __expf(-x));
}

__device__ __forceinline__ float dot4(float4 a, float4 b, float acc) {
    acc = fmaf(a.x, b.x, acc);
    acc = fmaf(a.y, b.y, acc);
    acc = fmaf(a.z, b.z, acc);
    acc = fmaf(a.w, b.w, acc);
    return acc;
}

// ---------------- leaves ----------------
// Block: 512 thr = 8 waves (jl = output j = blockIdx.x*8 + jl) x 64 lanes (kc).
// Thread's weight slice: k = 4*kc..4*kc+3 of row j for 3 gates = 12 floats in VGPRs,
// loaded coalesced from native row-major layout. 4 leaves per iteration via LDS.
__global__ __launch_bounds__(512, 4) void leaf_kernel(
    const int* __restrict__ word_ids, const float* __restrict__ emb,
    const float* __restrict__ Wi, const float* __restrict__ Wo, const float* __restrict__ Wu,
    const float* __restrict__ bi, const float* __restrict__ bo, const float* __restrict__ bu,
    float* __restrict__ h_buf, int n_leaves, int ncoh)
{
    const int tid = threadIdx.x;
    const int jb8 = blockIdx.x * 8;
    const int coh = blockIdx.y;
    const int kc  = tid & 63;
    const int jl  = tid >> 6;
    const int j   = jb8 + jl;

    __shared__ float s_e[4][H];

    const float4 wiv = *(const float4*)&Wi[(size_t)j * H + 4 * kc];
    const float4 wov = *(const float4*)&Wo[(size_t)j * H + 4 * kc];
    const float4 wuv = *(const float4*)&Wu[(size_t)j * H + 4 * kc];
    const float bij = bi[j], boj = bo[j], buj = bu[j];

    // staging role: thread stages s_e[sl][se], s_e[sl][se+1]
    const int sl = tid >> 7;            // leaf-sub 0..3
    const int se = (tid & 127) * 2;

    const int nq = (n_leaves + 3) >> 2; // leaf quads

    float2 v = make_float2(0.f, 0.f);
    {
        int l = coh * 4 + sl;
        if (l < n_leaves) {
            int wid = word_ids[l];
            v = *(const float2*)&emb[(size_t)wid * H + se];
        }
    }
    for (int q = coh; q < nq; q += ncoh) {
        __syncthreads();                 // s_e free
        *(float2*)&s_e[sl][se] = v;
        __syncthreads();                 // s_e ready
        int qn = q + ncoh;               // prefetch next quad's rows
        if (qn < nq) {
            int l = qn * 4 + sl;
            if (l < n_leaves) {
                int wid = word_ids[l];
                v = *(const float2*)&emb[(size_t)wid * H + se];
            }
        }
        float ai[4], ao[4], au[4];
#pragma unroll
        for (int lf = 0; lf < 4; ++lf) {
            float4 x = *(const float4*)&s_e[lf][4 * kc];
            ai[lf] = dot4(x, wiv, 0.f);
            ao[lf] = dot4(x, wov, 0.f);
            au[lf] = dot4(x, wuv, 0.f);
        }
#pragma unroll
        for (int m = 1; m <= 32; m <<= 1) {
#pragma unroll
            for (int lf = 0; lf < 4; ++lf) {
                ai[lf] += __shfl_xor(ai[lf], m);
                ao[lf] += __shfl_xor(ao[lf], m);
                au[lf] += __shfl_xor(au[lf], m);
            }
        }
        if (kc == 0) {
#pragma unroll
            for (int lf = 0; lf < 4; ++lf) {
                int l = q * 4 + lf;
                if (l < n_leaves) {
                    float ii = sigmoidf_(ai[lf] + bij);
                    float oo = sigmoidf_(ao[lf] + boj);
                    float uu = fmaxf(au[lf] + buj, 0.f);
                    float h  = oo * fmaxf(ii * uu, 0.f);
                    h_buf[(size_t)l * H + j] = h;
                }
            }
        }
    }
}

// ---------------- one tree level ----------------
// Same shape: thread's slice = 4 gates x 8 k (k = 4kc and 256+4kc) = 32 floats in VGPRs,
// loaded coalesced from native layout once per launch. LDS = cat[512] only.
__global__ __launch_bounds__(512, 4) void level_kernel(
    const int* __restrict__ left_idx, const int* __restrict__ right_idx,
    const float* __restrict__ Ui, const float* __restrict__ Uo, const float* __restrict__ Uu,
    const float* __restrict__ Uf1, const float* __restrict__ Uf2,
    const float* __restrict__ bui, const float* __restrict__ buo, const float* __restrict__ buu,
    const float* __restrict__ bf1, const float* __restrict__ bf2,
    float* __restrict__ h_buf, int tbase, int lvl, int n_leaves, int ncoh)
{
    const int tid = threadIdx.x;
    const int jb8 = blockIdx.x * 8;
    const int coh = blockIdx.y;
    const int kc  = tid & 63;
    const int jl  = tid >> 6;
    const int j   = jb8 + jl;

    __shared__ float s_cat[2 * H];

    const float4 wi0 = *(const float4*)&Ui[(size_t)j * 2 * H + 4 * kc];
    const float4 wi1 = *(const float4*)&Ui[(size_t)j * 2 * H + H + 4 * kc];
    const float4 wo0 = *(const float4*)&Uo[(size_t)j * 2 * H + 4 * kc];
    const float4 wo1 = *(const float4*)&Uo[(size_t)j * 2 * H + H + 4 * kc];
    const float4 wu0 = *(const float4*)&Uu[(size_t)j * 2 * H + 4 * kc];
    const float4 wu1 = *(const float4*)&Uu[(size_t)j * 2 * H + H + 4 * kc];
    const float4 wf0 = *(const float4*)&Uf1[(size_t)j * H + 4 * kc];
    const float4 wf1 = *(const float4*)&Uf2[(size_t)j * H + 4 * kc];
    const float b_i = bui[j], b_o = buo[j], b_u = buu[j];
    const float b_1 = bf1[j], b_2 = bf2[j];

    float v = 0.f;
    if (coh < lvl) {
        int t  = tbase + coh;
        int lc = __builtin_amdgcn_readfirstlane(left_idx[t]);
        int rc = __builtin_amdgcn_readfirstlane(right_idx[t]);
        v = (tid < H) ? h_buf[(size_t)lc * H + tid]
                      : h_buf[(size_t)rc * H + (tid - H)];
    }
    for (int idx = coh; idx < lvl; idx += ncoh) {
        __syncthreads();                 // s_cat free
        s_cat[tid] = v;
        __syncthreads();                 // s_cat ready
        int idxn = idx + ncoh;           // prefetch next node's children
        if (idxn < lvl) {
            int tn = tbase + idxn;
            int lc = __builtin_amdgcn_readfirstlane(left_idx[tn]);
            int rc = __builtin_amdgcn_readfirstlane(right_idx[tn]);
            v = (tid < H) ? h_buf[(size_t)lc * H + tid]
                          : h_buf[(size_t)rc * H + (tid - H)];
        }
        float4 x0 = *(const float4*)&s_cat[4 * kc];
        float4 x1 = *(const float4*)&s_cat[H + 4 * kc];
        float a_i = dot4(x0, wi0, 0.f); a_i = dot4(x1, wi1, a_i);
        float a_o = dot4(x0, wo0, 0.f); a_o = dot4(x1, wo1, a_o);
        float a_u = dot4(x0, wu0, 0.f); a_u = dot4(x1, wu1, a_u);
        float f1  = dot4(x0, wf0, 0.f);
        float f2  = dot4(x1, wf1, 0.f);
#pragma unroll
        for (int m = 1; m <= 32; m <<= 1) {
            a_i += __shfl_xor(a_i, m);
            a_o += __shfl_xor(a_o, m);
            a_u += __shfl_xor(a_u, m);
            f1  += __shfl_xor(f1,  m);
            f2  += __shfl_xor(f2,  m);
        }
        if (kc == 0) {
            float lh = s_cat[j];
            float rh = s_cat[H + j];
            float ii  = sigmoidf_(a_i + b_i);
            float oo  = sigmoidf_(a_o + b_o);
            float uu  = fmaxf(a_u + b_u, 0.f);
            float ff1 = sigmoidf_(f1 + b_1);
            float ff2 = sigmoidf_(f2 + b_2);
            float c   = ii * uu + ff1 * lh + ff2 * rh;
            float h   = oo * fmaxf(c, 0.f);
            h_buf[(size_t)(n_leaves + tbase + idx) * H + j] = h;
        }
    }
}

// ---------------- final projection ----------------
__global__ __launch_bounds__(256) void proj_kernel(
    const float* __restrict__ h_buf, const float* __restrict__ Wp,
    const float* __restrict__ bp, float* __restrict__ out, int total)
{
    int t = blockIdx.x * 256 + threadIdx.x;
    if (t >= total) return;
    int node = t / 5;
    int cls  = t - node * 5;
    const float4* hr = (const float4*)(h_buf + (size_t)node * H);
    const float4* wr = (const float4*)(Wp + (size_t)cls * H);
    float acc = 0.f;
#pragma unroll 8
    for (int k = 0; k < H / 4; ++k) {
        float4 a = hr[k], b = wr[k];
        acc += a.x * b.x + a.y * b.y + a.z * b.z + a.w * b.w;
    }
    out[t] = acc + bp[cls];
}

extern "C" void kernel_launch(void* const* d_in, const int* in_sizes, int n_in,
                              void* d_out, int out_size, void* d_ws, size_t ws_size,
                              hipStream_t stream)
{
    const int*   word_ids  = (const int*)  d_in[0];
    const int*   left_idx  = (const int*)  d_in[1];
    const int*   right_idx = (const int*)  d_in[2];
    const float* emb       = (const float*)d_in[3];
    const float* Wi  = (const float*)d_in[4];  const float* bi  = (const float*)d_in[5];
    const float* Wo  = (const float*)d_in[6];  const float* bo  = (const float*)d_in[7];
    const float* Wu  = (const float*)d_in[8];  const float* bu  = (const float*)d_in[9];
    const float* Ui  = (const float*)d_in[10]; const float* bui = (const float*)d_in[11];
    const float* Uo  = (const float*)d_in[12]; const float* buo = (const float*)d_in[13];
    const float* Uu  = (const float*)d_in[14]; const float* buu = (const float*)d_in[15];
    const float* Uf1 = (const float*)d_in[16]; const float* bf1 = (const float*)d_in[17];
    const float* Uf2 = (const float*)d_in[18]; const float* bf2 = (const float*)d_in[19];
    const float* Wp  = (const float*)d_in[20]; const float* bp  = (const float*)d_in[21];

    const int n_leaves   = in_sizes[0];
    const int n_internal = in_sizes[1];
    const int n_nodes    = n_leaves + n_internal;
    (void)n_in; (void)out_size; (void)ws_size;

    float* h_buf = (float*)d_ws;   // [n_nodes][H]

    // 1) leaves: grid = 32 j-splits x ncoh cohorts, 4 leaves per iteration
    int nq = (n_leaves + 3) >> 2;
    int ncohL = nq < 32 ? nq : 32;
    leaf_kernel<<<dim3(32, ncohL), 512, 0, stream>>>(
        word_ids, emb, Wi, Wo, Wu, bi, bo, bu, h_buf, n_leaves, ncohL);

    // 2) internal levels, one launch each (stream order = level dependency)
    int frontier = n_leaves;
    int tbase = 0;
    while (frontier > 1) {
        int lvl  = frontier >> 1;
        int ncoh = lvl < 32 ? lvl : 32;
        level_kernel<<<dim3(32, ncoh), 512, 0, stream>>>(
            left_idx, right_idx, Ui, Uo, Uu, Uf1, Uf2,
            bui, buo, buu, bf1, bf2, h_buf, tbase, lvl, n_leaves, ncoh);
        tbase += lvl;
        frontier = lvl + (frontier & 1);
    }

    // 3) projection
    int total = n_nodes * 5;
    proj_kernel<<<(total + 255) / 256, 256, 0, stream>>>(h_buf, Wp, bp, (float*)d_out, total);
}

// Round 9
// 314.081 us; speedup vs baseline: 2.8324x; 1.1370x over previous
//
#include <hip/hip_runtime.h>
#include <math.h>

#define H 256

__device__ __forceinline__ float sigmoidf_(float x) {
    return 1.0f / (1.0f + __expf(-x));
}

__device__ __forceinline__ float dot4(float4 a, float4 b, float acc) {
    acc = fmaf(a.x, b.x, acc);
    acc = fmaf(a.y, b.y, acc);
    acc = fmaf(a.z, b.z, acc);
    acc = fmaf(a.w, b.w, acc);
    return acc;
}

// DPP row ops: VALU-pipe cross-lane (NOT the shared DS pipe like __shfl).
// row_shl:n  => dst[i] = src[i+n] within each 16-lane row (data moves toward
// lane 0; bound_ctrl=1 -> out-of-row reads 0). Reduction accumulates at lane 0.
#define ROW_SHL1 0x101
#define ROW_SHL2 0x102
#define ROW_SHL4 0x104
#define ROW_SHL8 0x108

template<int CTRL>
__device__ __forceinline__ float dpp_addf(float v) {
    int s = __builtin_amdgcn_update_dpp(0, __float_as_int(v), CTRL, 0xF, 0xF, true);
    return v + __int_as_float(s);
}
template<int CTRL>
__device__ __forceinline__ float dpp_movf(float v) {
    int s = __builtin_amdgcn_update_dpp(0, __float_as_int(v), CTRL, 0xF, 0xF, true);
    return __int_as_float(s);
}

// ---------------- leaves ----------------
// Wave = 4 j (jl = lane>>4) x 16 k-lanes (ks = lane&15). Block 256 thr = 16 j.
// grid = (16 j-splits, ncoh cohorts). Weights: 48 floats/thread in VGPRs.
// No LDS, no barriers; e-row chunks loaded per-lane from global, 1-ahead pipelined.
__global__ __launch_bounds__(256) void leaf_kernel(
    const int* __restrict__ word_ids, const float* __restrict__ emb,
    const float* __restrict__ Wi, const float* __restrict__ Wo, const float* __restrict__ Wu,
    const float* __restrict__ bi, const float* __restrict__ bo, const float* __restrict__ bu,
    float* __restrict__ h_buf, int n_leaves, int ncoh)
{
    const int tid  = threadIdx.x;
    const int lane = tid & 63;
    const int wv   = tid >> 6;
    const int ks   = lane & 15;
    const int jl   = lane >> 4;
    const int j    = blockIdx.x * 16 + wv * 4 + jl;
    const int coh  = blockIdx.y;

    float4 wi[4], wo[4], wu[4];
    {
        const float4* pi = (const float4*)(Wi + (size_t)j * H + ks * 16);
        const float4* po = (const float4*)(Wo + (size_t)j * H + ks * 16);
        const float4* pu = (const float4*)(Wu + (size_t)j * H + ks * 16);
#pragma unroll
        for (int c = 0; c < 4; ++c) { wi[c] = pi[c]; wo[c] = po[c]; wu[c] = pu[c]; }
    }
    const float bij = bi[j], boj = bo[j], buj = bu[j];

    float4 px[4];
    if (coh < n_leaves) {
        int wid = word_ids[coh];
        const float4* pe = (const float4*)(emb + (size_t)wid * H + ks * 16);
#pragma unroll
        for (int c = 0; c < 4; ++c) px[c] = pe[c];
    }
    for (int l = coh; l < n_leaves; l += ncoh) {
        float ai = 0.f, ao = 0.f, au = 0.f;
#pragma unroll
        for (int c = 0; c < 4; ++c) {
            ai = dot4(px[c], wi[c], ai);
            ao = dot4(px[c], wo[c], ao);
            au = dot4(px[c], wu[c], au);
        }
        int ln = l + ncoh;                // px dead -> refill for next leaf
        if (ln < n_leaves) {
            int wid = word_ids[ln];
            const float4* pe = (const float4*)(emb + (size_t)wid * H + ks * 16);
#pragma unroll
            for (int c = 0; c < 4; ++c) px[c] = pe[c];
        }
        ai = dpp_addf<ROW_SHL8>(ai); ai = dpp_addf<ROW_SHL4>(ai);
        ai = dpp_addf<ROW_SHL2>(ai); ai = dpp_addf<ROW_SHL1>(ai);
        ao = dpp_addf<ROW_SHL8>(ao); ao = dpp_addf<ROW_SHL4>(ao);
        ao = dpp_addf<ROW_SHL2>(ao); ao = dpp_addf<ROW_SHL1>(ao);
        au = dpp_addf<ROW_SHL8>(au); au = dpp_addf<ROW_SHL4>(au);
        au = dpp_addf<ROW_SHL2>(au); au = dpp_addf<ROW_SHL1>(au);
        if (ks == 0) {
            float iv = sigmoidf_(ai + bij);
            float ov = sigmoidf_(ao + boj);
            float uv = fmaxf(au + buj, 0.f);
            float h  = ov * fmaxf(iv * uv, 0.f);
            h_buf[(size_t)l * H + j] = h;
        }
    }
}

// ---------------- one tree level ----------------
// Same shape. Thread weight slice: i,o,u rows (32 k each) + f (Uf1 if ks<8 else Uf2)
// = 128 floats in VGPRs. x-chunk = cat[ks*32..+31] straight from h_buf (global).
// Child indices prefetched 2-ahead, x 1-ahead. No LDS, no barriers.
__global__ __launch_bounds__(256) void level_kernel(
    const int* __restrict__ left_idx, const int* __restrict__ right_idx,
    const float* __restrict__ Ui, const float* __restrict__ Uo, const float* __restrict__ Uu,
    const float* __restrict__ Uf1, const float* __restrict__ Uf2,
    const float* __restrict__ bui, const float* __restrict__ buo, const float* __restrict__ buu,
    const float* __restrict__ bf1, const float* __restrict__ bf2,
    float* __restrict__ h_buf, int tbase, int lvl, int n_leaves, int ncoh)
{
    const int tid  = threadIdx.x;
    const int lane = tid & 63;
    const int wv   = tid >> 6;
    const int ks   = lane & 15;
    const int jl   = lane >> 4;
    const int j    = blockIdx.x * 16 + wv * 4 + jl;
    const int coh  = blockIdx.y;

    float4 wi[8], wo[8], wu[8], wf[8];
    {
        const float4* pi = (const float4*)(Ui + (size_t)j * 2 * H + ks * 32);
        const float4* po = (const float4*)(Uo + (size_t)j * 2 * H + ks * 32);
        const float4* pu = (const float4*)(Uu + (size_t)j * 2 * H + ks * 32);
        const float*  fr = (ks < 8) ? (Uf1 + (size_t)j * H + ks * 32)
                                    : (Uf2 + (size_t)j * H + (ks - 8) * 32);
        const float4* pf = (const float4*)fr;
#pragma unroll
        for (int c = 0; c < 8; ++c) { wi[c]=pi[c]; wo[c]=po[c]; wu[c]=pu[c]; wf[c]=pf[c]; }
    }
    const float b_i = bui[j], b_o = buo[j], b_u = buu[j];
    const float b_1 = bf1[j], b_2 = bf2[j];

    float4 px[8];
    float  plh = 0.f, prh = 0.f;
    int lc2 = 0, rc2 = 0;
    if (coh < lvl) {
        int lc = left_idx[tbase + coh];
        int rc = right_idx[tbase + coh];
        const float4* xb = (const float4*)((ks < 8)
            ? h_buf + (size_t)lc * H + ks * 32
            : h_buf + (size_t)rc * H + (ks - 8) * 32);
#pragma unroll
        for (int c = 0; c < 8; ++c) px[c] = xb[c];
        if (ks == 0) {
            plh = h_buf[(size_t)lc * H + j];
            prh = h_buf[(size_t)rc * H + j];
        }
        int i2 = coh + ncoh;
        if (i2 < lvl) { lc2 = left_idx[tbase + i2]; rc2 = right_idx[tbase + i2]; }
    }

    for (int idx = coh; idx < lvl; idx += ncoh) {
        float lh = plh, rh = prh;
        float ai = 0.f, ao = 0.f, au = 0.f, af = 0.f;
#pragma unroll
        for (int c = 0; c < 8; ++c) {
            ai = dot4(px[c], wi[c], ai);
            ao = dot4(px[c], wo[c], ao);
            au = dot4(px[c], wu[c], au);
            af = dot4(px[c], wf[c], af);
        }
        int idxn = idx + ncoh;            // px dead -> refill for next node
        if (idxn < lvl) {
            const float4* xb = (const float4*)((ks < 8)
                ? h_buf + (size_t)lc2 * H + ks * 32
                : h_buf + (size_t)rc2 * H + (ks - 8) * 32);
#pragma unroll
            for (int c = 0; c < 8; ++c) px[c] = xb[c];
            if (ks == 0) {
                plh = h_buf[(size_t)lc2 * H + j];
                prh = h_buf[(size_t)rc2 * H + j];
            }
            int idx2 = idxn + ncoh;       // indices 2-ahead
            if (idx2 < lvl) { lc2 = left_idx[tbase + idx2]; rc2 = right_idx[tbase + idx2]; }
        }
        // i,o,u: full 16-lane sum -> lane ks==0
        ai = dpp_addf<ROW_SHL8>(ai); ai = dpp_addf<ROW_SHL4>(ai);
        ai = dpp_addf<ROW_SHL2>(ai); ai = dpp_addf<ROW_SHL1>(ai);
        ao = dpp_addf<ROW_SHL8>(ao); ao = dpp_addf<ROW_SHL4>(ao);
        ao = dpp_addf<ROW_SHL2>(ao); ao = dpp_addf<ROW_SHL1>(ao);
        au = dpp_addf<ROW_SHL8>(au); au = dpp_addf<ROW_SHL4>(au);
        au = dpp_addf<ROW_SHL2>(au); au = dpp_addf<ROW_SHL1>(au);
        // f: 8-lane group sums (lane0 = Uf1 part over lanes 0-7,
        // lane8 = Uf2 part over lanes 8-15), then pull f2 to lane 0.
        af = dpp_addf<ROW_SHL4>(af); af = dpp_addf<ROW_SHL2>(af);
        af = dpp_addf<ROW_SHL1>(af);
        float f2s = dpp_movf<ROW_SHL8>(af);   // lane0 <- lane8's sum

        float iv  = sigmoidf_(ai + b_i);
        float ov  = sigmoidf_(ao + b_o);
        float uv  = fmaxf(au + b_u, 0.f);
        float f1v = sigmoidf_(af + b_1);
        float f2v = sigmoidf_(f2s + b_2);
        float cc  = iv * uv + f1v * lh + f2v * rh;
        float h   = ov * fmaxf(cc, 0.f);
        if (ks == 0)
            h_buf[(size_t)(n_leaves + tbase + idx) * H + j] = h;
    }
}

// ---------------- final projection ----------------
__global__ __launch_bounds__(256) void proj_kernel(
    const float* __restrict__ h_buf, const float* __restrict__ Wp,
    const float* __restrict__ bp, float* __restrict__ out, int total)
{
    int t = blockIdx.x * 256 + threadIdx.x;
    if (t >= total) return;
    int node = t / 5;
    int cls  = t - node * 5;
    const float4* hr = (const float4*)(h_buf + (size_t)node * H);
    const float4* wr = (const float4*)(Wp + (size_t)cls * H);
    float acc = 0.f;
#pragma unroll 8
    for (int k = 0; k < H / 4; ++k) {
        float4 a = hr[k], b = wr[k];
        acc += a.x * b.x + a.y * b.y + a.z * b.z + a.w * b.w;
    }
    out[t] = acc + bp[cls];
}

extern "C" void kernel_launch(void* const* d_in, const int* in_sizes, int n_in,
                              void* d_out, int out_size, void* d_ws, size_t ws_size,
                              hipStream_t stream)
{
    const int*   word_ids  = (const int*)  d_in[0];
    const int*   left_idx  = (const int*)  d_in[1];
    const int*   right_idx = (const int*)  d_in[2];
    const float* emb       = (const float*)d_in[3];
    const float* Wi  = (const float*)d_in[4];  const float* bi  = (const float*)d_in[5];
    const float* Wo  = (const float*)d_in[6];  const float* bo  = (const float*)d_in[7];
    const float* Wu  = (const float*)d_in[8];  const float* bu  = (const float*)d_in[9];
    const float* Ui  = (const float*)d_in[10]; const float* bui = (const float*)d_in[11];
    const float* Uo  = (const float*)d_in[12]; const float* buo = (const float*)d_in[13];
    const float* Uu  = (const float*)d_in[14]; const float* buu = (const float*)d_in[15];
    const float* Uf1 = (const float*)d_in[16]; const float* bf1 = (const float*)d_in[17];
    const float* Uf2 = (const float*)d_in[18]; const float* bf2 = (const float*)d_in[19];
    const float* Wp  = (const float*)d_in[20]; const float* bp  = (const float*)d_in[21];

    const int n_leaves   = in_sizes[0];
    const int n_internal = in_sizes[1];
    const int n_nodes    = n_leaves + n_internal;
    (void)n_in; (void)out_size; (void)ws_size;

    float* h_buf = (float*)d_ws;   // [n_nodes][H]

    // 1) leaves
    int ncohL = n_leaves < 64 ? n_leaves : 64;
    leaf_kernel<<<dim3(16, ncohL), 256, 0, stream>>>(
        word_ids, emb, Wi, Wo, Wu, bi, bo, bu, h_buf, n_leaves, ncohL);

    // 2) internal levels (stream order = level dependency)
    int frontier = n_leaves;
    int tbase = 0;
    while (frontier > 1) {
        int lvl  = frontier >> 1;
        int ncoh = lvl < 64 ? lvl : 64;
        level_kernel<<<dim3(16, ncoh), 256, 0, stream>>>(
            left_idx, right_idx, Ui, Uo, Uu, Uf1, Uf2,
            bui, buo, buu, bf1, bf2, h_buf, tbase, lvl, n_leaves, ncoh);
        tbase += lvl;
        frontier = lvl + (frontier & 1);
    }

    // 3) projection
    int total = n_nodes * 5;
    proj_kernel<<<(total + 255) / 256, 256, 0, stream>>>(h_buf, Wp, bp, (float*)d_out, total);
}